// Round 13
// baseline (64.760 us; speedup 1.0000x reference)
//
#include <hip/hip_runtime.h>
#include <math.h>

#define BB 4
#define NN 4096
#define DD 128
#define HS 8             // n slices per batch (512 n each)
#define NT2 16           // 32-n tiles per slice
#define QG 16            // m quad-groups per batch (256 m each; 4 waves x 64)

typedef __attribute__((ext_vector_type(8))) short bf16x8;
typedef __attribute__((ext_vector_type(4))) float f32x4;
typedef __attribute__((ext_vector_type(4))) unsigned short u16x4;

__device__ __forceinline__ void mfma_16x16x32_bf16(f32x4& d, bf16x8 a, bf16x8 b) {
  asm volatile("v_mfma_f32_16x16x32_bf16 %0, %1, %2, %0" : "+v"(d) : "v"(a), "v"(b));
}

__device__ __forceinline__ float vexp2(float x) {  // raw v_exp_f32 = 2^x
  float r; asm("v_exp_f32 %0, %1" : "=v"(r) : "v"(x)); return r;
}

__device__ __forceinline__ unsigned short f2b(float x) {  // RNE f32->bf16
  union { float f; unsigned u; } v; v.f = x;
  unsigned r = v.u + 0x7fffu + ((v.u >> 16) & 1u);
  return (unsigned short)(r >> 16);
}

// ---- kernel 1: cast to bf16 (ft pre-scaled by 0.1*log2e) + fs inv-norms ----
__global__ __launch_bounds__(256) void k_prep(const float* __restrict__ fs,
                                              const float* __restrict__ ft,
                                              unsigned short* __restrict__ fsb,
                                              unsigned short* __restrict__ ftb,
                                              float* __restrict__ inv_norm) {
  int i = blockIdx.x * 256 + threadIdx.x;    // float4 index
  float4 a = ((const float4*)fs)[i];
  float4 c = ((const float4*)ft)[i];
  u16x4 oa; oa[0] = f2b(a.x); oa[1] = f2b(a.y); oa[2] = f2b(a.z); oa[3] = f2b(a.w);
  ((u16x4*)fsb)[i] = oa;
  const float C = 0.14426950408889634f;      // 0.1*log2(e): 2^acc == exp(dot/10)
  u16x4 oc; oc[0] = f2b(c.x * C); oc[1] = f2b(c.y * C);
  oc[2] = f2b(c.z * C); oc[3] = f2b(c.w * C);
  ((u16x4*)ftb)[i] = oc;
  float s = a.x * a.x + a.y * a.y + a.z * a.z + a.w * a.w;
#pragma unroll
  for (int off = 1; off <= 16; off <<= 1) s += __shfl_xor(s, off);
  if ((threadIdx.x & 31) == 0) inv_norm[i >> 5] = 1.0f / sqrtf(s);
}

// ---- kernel 2: barrier-free reg-staged GEMM C[m][n], 64 m-rows per wave ----
// Wave owns 64 m-rows of ft (af[4][4]=64 VGPR, loaded once) and streams its
// 512-n fs slice in 16 tiles of 32 n. B fragments load STRAIGHT TO REGISTERS
// with an explicit 2x-unrolled double buffer (bfA/bfB, static indices) -- no
// LDS staging, no in-loop barriers, no inter-wave convoy. launch_bounds(,2)
// gives the allocator ~256 VGPR so loads pipeline (round 6 failed at VGPR=64:
// compiler serialized every load behind its use). 4 waves/block share (b,h)
// for L1/L2 reuse; single end barrier combines psum partials via 10KB LDS.
__global__ __launch_bounds__(256, 2) void k_main(const unsigned short* __restrict__ fsb,
                                                 const unsigned short* __restrict__ ftb,
                                                 const float* __restrict__ inv_norm,
                                                 float* __restrict__ psum,
                                                 float2* __restrict__ pmax) {
  __shared__ float psb[4 * 512];     // per-wave exp-sum partials
  __shared__ float sInv[512];        // inv_norm slice

  const int t = threadIdx.x;
  const int w = t >> 6, lane = t & 63;
  const int l15 = lane & 15, g = lane >> 4;
  const int bid = blockIdx.x;
  const int qg = bid & 15, h = (bid >> 4) & 7, b = bid >> 7;
  const int m0 = qg * 256 + w * 64;

  // A fragments: ft rows m0..m0+63 (pre-scaled), loaded once: 64 VGPR
  const unsigned short* Ab = ftb + ((size_t)b * NN + m0) * DD;
  bf16x8 af[4][4];
#pragma unroll
  for (int kk = 0; kk < 4; kk++)
#pragma unroll
    for (int mf = 0; mf < 4; mf++)
      af[kk][mf] = *(const bf16x8*)(Ab + (mf * 16 + l15) * DD + kk * 32 + g * 8);

  // inv_norm slice -> LDS (2 floats/thread), published by the end of prologue
  sInv[t] = inv_norm[(size_t)b * NN + h * 512 + t];
  sInv[256 + t] = inv_norm[(size_t)b * NN + h * 512 + 256 + t];
  __syncthreads();

  // per-lane fragment base: row l15, K-chunk g (byte offsets within 8KB tile)
  const char* gBlane = (const char*)(fsb + ((size_t)b * NN + h * 512) * DD)
                       + l15 * 256 + g * 16;

  float bkey[4][4];
#pragma unroll
  for (int mf = 0; mf < 4; mf++)
#pragma unroll
    for (int j = 0; j < 4; j++) bkey[mf][j] = 0.0f;

  bf16x8 bfA[8], bfB[8];

  // tile load: 8 dwordx4 from one base + immediate offsets (fj*4096 + kk*64)
#define LOAD_TILE(dst, it)                                                   \
  {                                                                          \
    const char* p = gBlane + (it) * 8192;                                    \
    _Pragma("unroll")                                                        \
    for (int kk = 0; kk < 4; kk++) {                                         \
      dst[kk * 2 + 0] = *(const bf16x8*)(p + kk * 64);                       \
      dst[kk * 2 + 1] = *(const bf16x8*)(p + 4096 + kk * 64);                \
    }                                                                        \
  }

#define COMPUTE_TILE(bf, it)                                                 \
  {                                                                          \
    f32x4 acc[4][2] = {};                                                    \
    _Pragma("unroll")                                                        \
    for (int kk = 0; kk < 4; kk++)                                           \
      _Pragma("unroll")                                                      \
      for (int mf = 0; mf < 4; mf++) {                                       \
        mfma_16x16x32_bf16(acc[mf][0], af[kk][mf], bf[kk * 2 + 0]);          \
        mfma_16x16x32_bf16(acc[mf][1], af[kk][mf], bf[kk * 2 + 1]);          \
      }                                                                      \
    _Pragma("unroll")                                                        \
    for (int fj = 0; fj < 2; fj++) {                                         \
      float s = 0.0f;                                                        \
      _Pragma("unroll")                                                      \
      for (int mf = 0; mf < 4; mf++) {                                       \
        float e0 = vexp2(acc[mf][fj][0]), e1 = vexp2(acc[mf][fj][1]);        \
        float e2 = vexp2(acc[mf][fj][2]), e3 = vexp2(acc[mf][fj][3]);        \
        s += (e0 + e1) + (e2 + e3);                                          \
      }                                                                      \
      s += __shfl_xor(s, 16);                                                \
      s += __shfl_xor(s, 32);                                                \
      if (g == 0) psb[w * 512 + (it) * 32 + fj * 16 + l15] = s;              \
      float svn = sInv[(it) * 32 + fj * 16 + l15];                           \
      const unsigned code = (unsigned)((15 - (it)) << 1) | (unsigned)(1 - fj);\
      _Pragma("unroll")                                                      \
      for (int mf = 0; mf < 4; mf++)                                         \
        _Pragma("unroll")                                                    \
        for (int j = 0; j < 4; j++) {                                        \
          float v = fmaf(acc[mf][fj][j], svn, 4.0f);                         \
          unsigned kb = (__float_as_uint(v) & 0xFFFFFFE0u) | code;           \
          bkey[mf][j] = fmaxf(bkey[mf][j], __uint_as_float(kb));             \
        }                                                                    \
    }                                                                        \
  }

  LOAD_TILE(bfA, 0)
#pragma unroll 1
  for (int itp = 0; itp < NT2 / 2; ++itp) {
    const int it0 = itp * 2, it1 = itp * 2 + 1;
    LOAD_TILE(bfB, it1)
    COMPUTE_TILE(bfA, it0)
    if (itp < NT2 / 2 - 1) LOAD_TILE(bfA, it1 + 1)
    COMPUTE_TILE(bfB, it1)
  }

  // pmax finalize: exact cross-l15 argmax, once per wave (64 private m-rows)
#pragma unroll
  for (int mf = 0; mf < 4; mf++)
#pragma unroll
    for (int j = 0; j < 4; j++) {
      unsigned bits = __float_as_uint(bkey[mf][j]);
      unsigned code = bits & 31u;
      int itw = 15 - (int)(code >> 1);
      int fjw = 1 - (int)(code & 1u);
      int n = h * 512 + itw * 32 + fjw * 16 + l15;
      float vq = __uint_as_float(bits & 0xFFFFFFE0u);
#pragma unroll
      for (int off = 1; off <= 8; off <<= 1) {
        float ov = __shfl_xor(vq, off);
        int   on = __shfl_xor(n, off);
        if (ov > vq || (ov == vq && on < n)) { vq = ov; n = on; }
      }
      if (l15 == 0) {
        int m = m0 + mf * 16 + g * 4 + j;
        float2 pr; pr.x = vq; pr.y = __int_as_float(n);
        pmax[((size_t)b * NN + m) * HS + h] = pr;
      }
    }

  __syncthreads();   // psb complete block-wide (only barrier after prologue)

  // psum write-out: combine 4 waves, coalesced (layout psum[b][qg][n])
#pragma unroll
  for (int rr = 0; rr < 2; rr++) {
    int nl = rr * 256 + t;
    float s4 = (psb[nl] + psb[512 + nl]) + (psb[1024 + nl] + psb[1536 + nl]);
    psum[((size_t)(b * QG + qg)) * NN + h * 512 + nl] = s4;
  }
#undef LOAD_TILE
#undef COMPUTE_TILE
}

// ---- kernel 3: per-row finish: argmax over 8 slices, sum 16 psum, pos dot --
__global__ __launch_bounds__(256) void k_post(const float* __restrict__ fs,
                                              const float* __restrict__ ft,
                                              const float* __restrict__ psum,
                                              const float2* __restrict__ pmax,
                                              float* __restrict__ blockpart) {
  __shared__ float part[4];
  int w = threadIdx.x >> 6, lane = threadIdx.x & 63;
  int row = blockIdx.x * 4 + w;          // flat b*N + p
  int b = row >> 12, pn = row & (NN - 1);
  // argmax over the 8 h-slices
  float v = -INFINITY; int i = 0x7fffffff;
  if (lane < HS) {
    float2 pm = pmax[(size_t)row * HS + lane];
    v = pm.x; i = __float_as_int(pm.y);
  }
#pragma unroll
  for (int off = 1; off <= 4; off <<= 1) {
    float ov = __shfl_xor(v, off);
    int   oi = __shfl_xor(i, off);
    if (ov > v || (ov == v && oi < i)) { v = ov; i = oi; }
  }
  int j = __shfl(i, 0);
  // sum the 16 q-partials of all_exp
  float tot = (lane < QG) ? psum[((size_t)(b * QG + lane)) * NN + pn] : 0.0f;
#pragma unroll
  for (int off = 1; off <= 8; off <<= 1) tot += __shfl_xor(tot, off);
  // fp32 dot of fs[row] with ft[b, j]
  float2 a = ((const float2*)(fs + (size_t)row * DD))[lane];
  float2 c = ((const float2*)(ft + ((size_t)b * NN + j) * DD))[lane];
  float s = a.x * c.x + a.y * c.y;
#pragma unroll
  for (int off = 32; off > 0; off >>= 1) s += __shfl_xor(s, off);
  if (lane == 0) {
    float term = logf(tot) - s * 0.1f;
    part[w] = fminf(term, 92.103403719761827f);   // ratio clip at 1e-40
  }
  __syncthreads();
  if (threadIdx.x == 0)
    blockpart[blockIdx.x] = part[0] + part[1] + part[2] + part[3];
}

// ---- kernel 4: final deterministic reduction ------------------------------
__global__ __launch_bounds__(256) void k_final(const float* __restrict__ blockpart,
                                               float* __restrict__ out) {
  __shared__ float red[256];
  float s = 0.0f;
  for (int i = threadIdx.x; i < (BB * NN) / 4; i += 256) s += blockpart[i];
  red[threadIdx.x] = s;
  __syncthreads();
  for (int st = 128; st > 0; st >>= 1) {
    if (threadIdx.x < st) red[threadIdx.x] += red[threadIdx.x + st];
    __syncthreads();
  }
  if (threadIdx.x == 0) out[0] = red[0] * (1.0f / (BB * NN));
}

extern "C" void kernel_launch(void* const* d_in, const int* in_sizes, int n_in,
                              void* d_out, int out_size, void* d_ws, size_t ws_size,
                              hipStream_t stream) {
  const float* fs = (const float*)d_in[0];
  const float* ft = (const float*)d_in[1];
  float* out = (float*)d_out;

  const size_t NE = (size_t)BB * NN * DD;
  unsigned short* fsb = (unsigned short*)d_ws;                   // 4MB
  unsigned short* ftb = fsb + NE;                                // 4MB
  float*  inv_norm = (float*)(ftb + NE);                         // 64KB
  float*  psum     = inv_norm + (size_t)BB * NN;                 // B*16*N f32 (1MB)
  float2* pmax     = (float2*)(psum + (size_t)BB * QG * NN);     // B*N*8 f32x2 (1MB)
  float*  blockpart = (float*)(pmax + (size_t)BB * NN * HS);     // B*N/4 f32

  k_prep<<<(int)(NE / 4 / 256), 256, 0, stream>>>(fs, ft, fsb, ftb, inv_norm);
  // k_main: b(4) x h(8) x qg(16) = 512 blocks, 2048 independent waves
  k_main<<<BB * HS * QG, 256, 0, stream>>>(fsb, ftb, inv_norm, psum, pmax);
  k_post<<<(BB * NN) / 4, 256, 0, stream>>>(fs, ft, psum, pmax, blockpart);
  k_final<<<1, 256, 0, stream>>>(blockpart, out);
}